// Round 8
// baseline (1881.998 us; speedup 1.0000x reference)
//
#include <hip/hip_runtime.h>

typedef unsigned short ushortT;
typedef __attribute__((ext_vector_type(8))) short short8v;
typedef __attribute__((ext_vector_type(4))) float float4v;

constexpr int D = 128;
constexpr int BKT_CAP = 8192;      // entries per bucket (mean ~4096 worst region)
constexpr int OVF_CAP = 1 << 20;   // overflow safety net

// ---------------------------------------------------------- split helpers
__device__ __forceinline__ void splitf(float v, short& h, short& l) {
    unsigned u = __float_as_uint(v);
    unsigned hb = u & 0xffff0000u;
    float r = v - __uint_as_float(hb);
    h = (short)(u >> 16);
    l = (short)(__float_as_uint(r) >> 16);
}
__device__ __forceinline__ unsigned packsplit(float v) {
    unsigned u = __float_as_uint(v);
    unsigned hb = u & 0xffff0000u;
    float r = v - __uint_as_float(hb);
    return hb | (__float_as_uint(r) >> 16);
}
__device__ __forceinline__ float unpackf(unsigned p) {
    return __uint_as_float(p & 0xffff0000u) + __uint_as_float(p << 16);
}

// ------------------------------------------- phase A: count + bucket edges
// bktCur padded: one cursor per 64B line (stride 16 ints).
__global__ void bucket_count(const int* __restrict__ ecc, const int* __restrict__ ekc,
                             const int* __restrict__ eck, int Ecc, int Ekc, int Eck,
                             int ncui, int* __restrict__ cnt, int* __restrict__ bktCur,
                             unsigned* __restrict__ bkt, int* __restrict__ ovfCnt,
                             int* __restrict__ ovf) {
    int ET = Ecc + Ekc + Eck;
    for (int e = blockIdx.x * blockDim.x + threadIdx.x; e < ET;
         e += gridDim.x * blockDim.x) {
        int d, s;
        if (e < Ecc)            { s = ecc[e]; d = ecc[Ecc + e]; }
        else if (e < Ecc + Ekc) { int le = e - Ecc; s = ekc[le]; d = ncui + ekc[Ekc + le]; }
        else                    { int le = e - Ecc - Ekc; s = eck[le]; d = 2 * ncui + eck[Eck + le]; }
        atomicAdd(&cnt[d], 1);
        int b = d >> 8;
        int p = atomicAdd(&bktCur[b * 16], 1);
        if (p < BKT_CAP) {
            bkt[(size_t)b * BKT_CAP + p] = ((unsigned)(d & 255) << 24) | (unsigned)s;
        } else {
            int q = atomicAdd(ovfCnt, 1);
            if (q < OVF_CAP) { ovf[q * 2] = s; ovf[q * 2 + 1] = d; }
        }
    }
}

// ------------------------------------------- phase B: L2-local placement
__global__ void bucket_place(const unsigned* __restrict__ bkt, const int* __restrict__ bktCur,
                             int* __restrict__ cur, int* __restrict__ csr) {
    int b = blockIdx.x;
    int n = bktCur[b * 16];
    if (n > BKT_CAP) n = BKT_CAP;
    int base = b << 8;
    for (int t = threadIdx.x; t < n; t += blockDim.x) {
        unsigned e = bkt[(size_t)b * BKT_CAP + t];
        int s = (int)(e & 0xFFFFFFu);
        int d = base + (int)(e >> 24);
        int p = atomicAdd(&cur[d], 1);
        csr[p] = s;
    }
}

// overflow drain (normally count==0; always launched for graph-capture safety)
__global__ void place_ovf(const int* __restrict__ ovfCnt, const int* __restrict__ ovf,
                          int* __restrict__ cur, int* __restrict__ csr) {
    int n = *ovfCnt;
    if (n > OVF_CAP) n = OVF_CAP;
    for (int i = blockIdx.x * blockDim.x + threadIdx.x; i < n;
         i += gridDim.x * blockDim.x) {
        int s = ovf[i * 2], d = ovf[i * 2 + 1];
        int p = atomicAdd(&cur[d], 1);
        csr[p] = s;
    }
}

// 3-phase multi-block exclusive scan over the concatenated count array.
__global__ __launch_bounds__(1024) void scan_s1(const int* __restrict__ cnt, int n4,
                                                int* __restrict__ blockSums) {
    __shared__ int red[1024];
    int t = threadIdx.x;
    int i = blockIdx.x * 1024 + t;
    int4 v = (i < n4) ? ((const int4*)cnt)[i] : make_int4(0, 0, 0, 0);
    red[t] = v.x + v.y + v.z + v.w;
    __syncthreads();
    for (int s = 512; s > 0; s >>= 1) {
        if (t < s) red[t] += red[t + s];
        __syncthreads();
    }
    if (t == 0) blockSums[blockIdx.x] = red[0];
}

__global__ __launch_bounds__(1024) void scan_s2(int* __restrict__ bs, int nb,
                                                int* __restrict__ offs, int NT) {
    __shared__ int s[1024];
    int t = threadIdx.x;
    int v = (t < nb) ? bs[t] : 0;
    s[t] = v;
    __syncthreads();
    for (int d = 1; d < 1024; d <<= 1) {
        int u = (t >= d) ? s[t - d] : 0;
        __syncthreads();
        s[t] += u;
        __syncthreads();
    }
    if (t < nb) bs[t] = s[t] - v;
    if (t == 0) offs[NT] = s[1023];
}

__global__ __launch_bounds__(1024) void scan_s3(const int* __restrict__ cnt, int n,
                                                const int* __restrict__ blockSums,
                                                int* __restrict__ offs, int* __restrict__ cur,
                                                float* __restrict__ inv) {
    __shared__ int sc[1024];
    int t = threadIdx.x;
    int n4 = n >> 2;
    int i4 = blockIdx.x * 1024 + t;
    int4 v = (i4 < n4) ? ((const int4*)cnt)[i4] : make_int4(0, 0, 0, 0);
    int s1 = v.x, s2 = s1 + v.y, s3 = s2 + v.z, s4 = s3 + v.w;
    sc[t] = s4;
    __syncthreads();
    for (int d = 1; d < 1024; d <<= 1) {
        int u = (t >= d) ? sc[t - d] : 0;
        __syncthreads();
        sc[t] += u;
        __syncthreads();
    }
    int base = sc[t] - s4 + blockSums[blockIdx.x];
    if (i4 < n4) {
        int4 o;
        o.x = base; o.y = base + s1; o.z = base + s2; o.w = base + s3;
        ((int4*)offs)[i4] = o;
        ((int4*)cur)[i4]  = o;
        float4 iv;
        iv.x = 1.f / fmaxf((float)v.x, 1.f);
        iv.y = 1.f / fmaxf((float)v.y, 1.f);
        iv.z = 1.f / fmaxf((float)v.z, 1.f);
        iv.w = 1.f / fmaxf((float)v.w, 1.f);
        ((float4*)inv)[i4] = iv;
    }
}

// --------------------------------- weight reorder to MFMA-frag-major hi/lo
__global__ void prep_w(const float* __restrict__ Wl, const float* __restrict__ Wr,
                       const float* __restrict__ b, ushortT* __restrict__ Wp,
                       float* __restrict__ bcomb) {
    if (blockIdx.x == 160) {
        for (int t = threadIdx.x; t < 512; t += 256) {
            int fl = t >> 7, c = t & 127;
            bcomb[t] = b[(fl * 3 + 0) * D + c] + b[(fl * 3 + 1) * D + c];
        }
        return;
    }
    int id = blockIdx.x * 256 + threadIdx.x;
    int mat = id >> 11;
    int slot = id & 2047;
    int nt = slot >> 8, rem = slot & 255, ks = rem >> 6, lane = rem & 63;
    int row = nt * 16 + (lane & 15);
    int k0 = ks * 32 + ((lane >> 4) << 3);
    int fl = mat / 5, j = mat % 5;
    const float* s1;
    const float* s2 = nullptr;
    if (j < 2)       s1 = Wl + (size_t)(fl * 3 + j) * D * D;
    else if (j == 2) { s1 = Wr + (size_t)(fl * 3 + 0) * D * D;
                       s2 = Wr + (size_t)(fl * 3 + 1) * D * D; }
    else if (j == 3) s1 = Wl + (size_t)(fl * 3 + 2) * D * D;
    else             s1 = Wr + (size_t)(fl * 3 + 2) * D * D;

    unsigned hw[4], lw[4];
    #pragma unroll
    for (int q = 0; q < 4; ++q) {
        short h0, l0, h1, l1;
        float v0 = s1[row * D + k0 + 2 * q];
        float v1 = s1[row * D + k0 + 2 * q + 1];
        if (s2) { v0 += s2[row * D + k0 + 2 * q]; v1 += s2[row * D + k0 + 2 * q + 1]; }
        splitf(v0, h0, l0);
        splitf(v1, h1, l1);
        hw[q] = (unsigned short)h0 | ((unsigned)(unsigned short)h1 << 16);
        lw[q] = (unsigned short)l0 | ((unsigned)(unsigned short)l1 << 16);
    }
    ushortT* dh = Wp + (size_t)mat * 32768 + slot * 8;
    *(uint4*)dh           = make_uint4(hw[0], hw[1], hw[2], hw[3]);
    *(uint4*)(dh + 16384) = make_uint4(lw[0], lw[1], lw[2], lw[3]);
}

// ----------------------------------------------------- CSR mean aggregation
// One wave per global dst row; lane handles 2 cols; 8 rows in flight.
__global__ void agg_all(const float* __restrict__ src_cui_f, const float* __restrict__ src_code_f,
                        const unsigned* __restrict__ src_cui_p, const unsigned* __restrict__ src_code_p,
                        int packed, const int* __restrict__ csr, const int* __restrict__ offs,
                        const float* __restrict__ inv, int ncui, int ncode,
                        unsigned* __restrict__ outP) {
    int NT = 2 * ncui + ncode;
    int gw = (int)((blockIdx.x * (size_t)blockDim.x + threadIdx.x) >> 6);
    int lane = threadIdx.x & 63;
    if (gw >= NT) return;
    bool isCode = (gw >= ncui) && (gw < 2 * ncui);
    int st = offs[gw], en = offs[gw + 1];
    float ax[8], ay[8];
    #pragma unroll
    for (int j = 0; j < 8; ++j) { ax[j] = 0.f; ay[j] = 0.f; }
    int e = st;
    if (!packed) {
        const float* s = isCode ? src_code_f : src_cui_f;
        for (; e + 8 <= en; e += 8) {
            int idx[8];
            #pragma unroll
            for (int j = 0; j < 8; ++j) idx[j] = csr[e + j];
            #pragma unroll
            for (int j = 0; j < 8; ++j) {
                float2 q = ((const float2*)(s + (size_t)idx[j] * D))[lane];
                ax[j] += q.x; ay[j] += q.y;
            }
        }
        for (; e + 4 <= en; e += 4) {
            int idx[4];
            #pragma unroll
            for (int j = 0; j < 4; ++j) idx[j] = csr[e + j];
            #pragma unroll
            for (int j = 0; j < 4; ++j) {
                float2 q = ((const float2*)(s + (size_t)idx[j] * D))[lane];
                ax[j] += q.x; ay[j] += q.y;
            }
        }
        for (; e < en; ++e) {
            float2 q = ((const float2*)(s + (size_t)csr[e] * D))[lane];
            ax[0] += q.x; ay[0] += q.y;
        }
    } else {
        const unsigned* s = isCode ? src_code_p : src_cui_p;
        for (; e + 8 <= en; e += 8) {
            int idx[8];
            #pragma unroll
            for (int j = 0; j < 8; ++j) idx[j] = csr[e + j];
            #pragma unroll
            for (int j = 0; j < 8; ++j) {
                uint2 q = ((const uint2*)(s + (size_t)idx[j] * D))[lane];
                ax[j] += unpackf(q.x); ay[j] += unpackf(q.y);
            }
        }
        for (; e + 4 <= en; e += 4) {
            int idx[4];
            #pragma unroll
            for (int j = 0; j < 4; ++j) idx[j] = csr[e + j];
            #pragma unroll
            for (int j = 0; j < 4; ++j) {
                uint2 q = ((const uint2*)(s + (size_t)idx[j] * D))[lane];
                ax[j] += unpackf(q.x); ay[j] += unpackf(q.y);
            }
        }
        for (; e < en; ++e) {
            uint2 q = ((const uint2*)(s + (size_t)csr[e] * D))[lane];
            ax[0] += unpackf(q.x); ay[0] += unpackf(q.y);
        }
    }
    float sc = inv[gw];
    float r0 = (((ax[0] + ax[1]) + (ax[2] + ax[3])) + ((ax[4] + ax[5]) + (ax[6] + ax[7]))) * sc;
    float r1 = (((ay[0] + ay[1]) + (ay[2] + ay[3])) + ((ay[4] + ay[5]) + (ay[6] + ay[7]))) * sc;
    ((uint2*)(outP + (size_t)gw * D))[lane] = make_uint2(packsplit(r0), packsplit(r1));
}

// -------------------------------------------------- split-bf16 MFMA GEMM
__global__ __launch_bounds__(256, 2) void gemm_split(
    const unsigned* __restrict__ A0, const unsigned* __restrict__ A1,
    const unsigned* __restrict__ A2, const float* __restrict__ Alast_f32,
    const ushortT* __restrict__ W0, const ushortT* __restrict__ W1,
    const ushortT* __restrict__ W2, const float* __restrict__ bias,
    float* __restrict__ outF, unsigned* __restrict__ outP,
    int M, int nPairs, int mode) {
    __shared__ ushortT wlds[32768];

    int tid = threadIdx.x;
    int lane = tid & 63;
    int w = tid >> 6;
    int rowTile = blockIdx.x * 256 + w * 64;
    int rl = lane & 15;
    int kg = (lane >> 4) << 3;

    float4v acc[4][8];
    #pragma unroll
    for (int mt = 0; mt < 4; ++mt)
        #pragma unroll
        for (int nt = 0; nt < 8; ++nt)
            acc[mt][nt] = (float4v){0.f, 0.f, 0.f, 0.f};

    const unsigned* Aarr[3] = {A0, A1, A2};
    const ushortT* Warr[3] = {W0, W1, W2};

    for (int p = 0; p < nPairs; ++p) {
        __syncthreads();
        {
            const ushortT* Wsrc = Warr[p];
            #pragma unroll
            for (int i = 0; i < 16; ++i)
                *(int4*)&wlds[i * 2048 + tid * 8] = *(const int4*)&Wsrc[i * 2048 + tid * 8];
        }
        __syncthreads();
        bool f32A = (Alast_f32 != nullptr) && (p == nPairs - 1);
        const unsigned* A = Aarr[p];
        #pragma unroll
        for (int ks = 0; ks < 4; ++ks) {
            short8v ah[4], al[4];
            #pragma unroll
            for (int mt = 0; mt < 4; ++mt) {
                int row = rowTile + mt * 16 + rl;
                if (row < M) {
                    size_t boff = (size_t)row * D + ks * 32 + kg;
                    if (!f32A) {
                        uint4 q0 = *(const uint4*)(A + boff);
                        uint4 q1 = *(const uint4*)(A + boff + 4);
                        unsigned qa[8] = {q0.x, q0.y, q0.z, q0.w, q1.x, q1.y, q1.z, q1.w};
                        #pragma unroll
                        for (int jj = 0; jj < 8; ++jj) {
                            ah[mt][jj] = (short)(qa[jj] >> 16);
                            al[mt][jj] = (short)(qa[jj] & 0xffffu);
                        }
                    } else {
                        float4 f0 = *(const float4*)(Alast_f32 + boff);
                        float4 f1 = *(const float4*)(Alast_f32 + boff + 4);
                        float fa[8] = {f0.x, f0.y, f0.z, f0.w, f1.x, f1.y, f1.z, f1.w};
                        #pragma unroll
                        for (int jj = 0; jj < 8; ++jj) {
                            short hh, ll;
                            splitf(fa[jj], hh, ll);
                            ah[mt][jj] = hh;
                            al[mt][jj] = ll;
                        }
                    }
                } else {
                    #pragma unroll
                    for (int jj = 0; jj < 8; ++jj) { ah[mt][jj] = 0; al[mt][jj] = 0; }
                }
            }
            #pragma unroll
            for (int nt = 0; nt < 8; ++nt) {
                short8v bh = *(const short8v*)&wlds[nt * 2048 + ks * 512 + lane * 8];
                short8v bl = *(const short8v*)&wlds[16384 + nt * 2048 + ks * 512 + lane * 8];
                #pragma unroll
                for (int mt = 0; mt < 4; ++mt)
                    acc[mt][nt] = __builtin_amdgcn_mfma_f32_16x16x32_bf16(ah[mt], bh, acc[mt][nt], 0, 0, 0);
                #pragma unroll
                for (int mt = 0; mt < 4; ++mt)
                    acc[mt][nt] = __builtin_amdgcn_mfma_f32_16x16x32_bf16(ah[mt], bl, acc[mt][nt], 0, 0, 0);
                #pragma unroll
                for (int mt = 0; mt < 4; ++mt)
                    acc[mt][nt] = __builtin_amdgcn_mfma_f32_16x16x32_bf16(al[mt], bh, acc[mt][nt], 0, 0, 0);
            }
        }
    }

    #pragma unroll
    for (int nt = 0; nt < 8; ++nt) {
        int col = nt * 16 + rl;
        float bv = bias[col];
        #pragma unroll
        for (int mt = 0; mt < 4; ++mt) {
            int r0 = rowTile + mt * 16 + ((lane >> 4) << 2);
            float4v c = acc[mt][nt];
            #pragma unroll
            for (int r = 0; r < 4; ++r) {
                int row = r0 + r;
                if (row >= M) continue;
                float v = c[r] + bv;
                if (mode == 0) {
                    v = fmaxf(v, 0.f);
                    outP[(size_t)row * D + col] = packsplit(v);
                } else if (mode == 1) {
                    outF[(size_t)row * D + col] = v;
                } else {
                    float* pp = outF + (size_t)row * D + col;
                    *pp = fmaxf(*pp, v);
                }
            }
        }
    }
}

// ------------------------------------------------------------------- driver
extern "C" void kernel_launch(void* const* d_in, const int* in_sizes, int n_in,
                              void* d_out, int out_size, void* d_ws, size_t ws_size,
                              hipStream_t stream) {
    const float* x_cui  = (const float*)d_in[0];
    const float* x_code = (const float*)d_in[1];
    const int*   ei_cc  = (const int*)d_in[2];
    const int*   ei_kc  = (const int*)d_in[3];
    const int*   ei_ck  = (const int*)d_in[4];
    const float* Wl     = (const float*)d_in[5];
    const float* Wr     = (const float*)d_in[6];
    const float* b      = (const float*)d_in[7];

    const int N_CUI  = in_sizes[0] / D;
    const int N_CODE = in_sizes[1] / D;
    const int E_CC   = in_sizes[2] / 2;
    const int E_KC   = in_sizes[3] / 2;
    const int E_CK   = in_sizes[4] / 2;
    const int NT = 2 * N_CUI + N_CODE;
    const int ET = E_CC + E_KC + E_CK;
    const int NB = (NT + 255) >> 8;          // buckets

    char* ws = (char*)d_ws;
    size_t off = 0;
    auto alloc = [&](size_t bytes) -> char* {
        char* p = ws + off;
        off += (bytes + 255) & ~(size_t)255;
        return p;
    };

    // zero-init region (one memset): cnt + padded bucket cursors + ovf cursor
    int*      cntAll    = (int*)alloc((size_t)NT * 4);
    int*      bktCur    = (int*)alloc((size_t)NB * 16 * 4);
    int*      ovfCnt    = (int*)alloc(64);
    size_t cntBytes = off;

    int*      offsAll   = (int*)alloc(((size_t)NT + 4) * 4);
    int*      curAll    = (int*)alloc((size_t)NT * 4);
    float*    invAll    = (float*)alloc((size_t)NT * 4);
    int*      blockSums = (int*)alloc(1024 * 4);
    int*      csrAll    = (int*)alloc((size_t)ET * 4);
    ushortT*  Wp        = (ushortT*)alloc((size_t)20 * 32768 * 2);
    float*    bcomb     = (float*)alloc(512 * 4);
    unsigned* aggP      = (unsigned*)alloc((size_t)NT * D * 4);
    unsigned* hcuiP0    = (unsigned*)alloc((size_t)N_CUI * D * 4);
    unsigned* hcuiP1    = (unsigned*)alloc((size_t)N_CUI * D * 4);
    unsigned* hcodeP0   = (unsigned*)alloc((size_t)N_CODE * D * 4);
    unsigned* hcodeP1   = (unsigned*)alloc((size_t)N_CODE * D * 4);

    // bkt/ovf ALIASED into aggP: used only during CSR build, which completes
    // (stream-ordered) before the first agg_all writes aggP. 40.4MB < 128MB.
    // Keeps total ws footprint identical to the proven-good R3 layout.
    unsigned* bkt = aggP;
    int*      ovf = (int*)(aggP + (size_t)NB * BKT_CAP);

    float* out_cui  = (float*)d_out;
    float* out_code = (float*)d_out + (size_t)N_CUI * D;

    unsigned* hcP[2] = {hcuiP0, hcuiP1};
    unsigned* hkP[2] = {hcodeP0, hcodeP1};

    const unsigned* aggCC = aggP;
    const unsigned* aggKC = aggP + (size_t)N_CUI * D;
    const unsigned* aggCK = aggP + (size_t)2 * N_CUI * D;

    // ---- CSR build: bucket, scan, place ----
    hipMemsetAsync(d_ws, 0, cntBytes, stream);
    bucket_count<<<2048, 256, 0, stream>>>(ei_cc, ei_kc, ei_ck, E_CC, E_KC, E_CK,
                                           N_CUI, cntAll, bktCur, bkt, ovfCnt, ovf);
    int n4 = NT >> 2;
    int nb = (n4 + 1023) / 1024;
    scan_s1<<<nb, 1024, 0, stream>>>(cntAll, n4, blockSums);
    scan_s2<<<1, 1024, 0, stream>>>(blockSums, nb, offsAll, NT);
    scan_s3<<<nb, 1024, 0, stream>>>(cntAll, NT, blockSums, offsAll, curAll, invAll);
    bucket_place<<<NB, 256, 0, stream>>>(bkt, bktCur, curAll, csrAll);
    place_ovf<<<64, 256, 0, stream>>>(ovfCnt, ovf, curAll, csrAll);
    prep_w<<<161, 256, 0, stream>>>(Wl, Wr, b, Wp, bcomb);

    int aggGrid = (NT + 3) / 4;
    int gCui = (N_CUI + 255) / 256;
    int gCode = (N_CODE + 255) / 256;
    auto WpM = [&](int m) { return (const ushortT*)(Wp + (size_t)m * 32768); };

    // ---- layer 0: shared aggregation, then per-filter transforms ----
    agg_all<<<aggGrid, 256, 0, stream>>>(x_cui, x_code, nullptr, nullptr, 0,
                                         csrAll, offsAll, invAll, N_CUI, N_CODE, aggP);
    for (int f = 0; f < 2; ++f) {
        int fl = f * 2;
        gemm_split<<<gCui, 256, 0, stream>>>(
            aggCC, aggKC, aggCC /*unused*/, x_cui,
            WpM(fl * 5 + 0), WpM(fl * 5 + 1), WpM(fl * 5 + 2),
            bcomb + fl * D, nullptr, hcP[f], N_CUI, 3, 0);
    }
    for (int f = 0; f < 2; ++f) {
        int fl = f * 2;
        gemm_split<<<gCode, 256, 0, stream>>>(
            aggCK, aggCK /*unused*/, aggCK /*unused*/, x_code,
            WpM(fl * 5 + 3), WpM(fl * 5 + 4), WpM(fl * 5 + 4),
            b + (size_t)(fl * 3 + 2) * D, nullptr, hkP[f], N_CODE, 2, 0);
    }

    // ---- layer 1: per-filter aggregation + final transforms ----
    for (int f = 0; f < 2; ++f) {
        int fl = f * 2 + 1;
        int mode = (f == 0) ? 1 : 2;
        agg_all<<<aggGrid, 256, 0, stream>>>(nullptr, nullptr, hcP[f], hkP[f], 1,
                                             csrAll, offsAll, invAll, N_CUI, N_CODE, aggP);
        gemm_split<<<gCui, 256, 0, stream>>>(
            aggCC, aggKC, hcP[f], nullptr,
            WpM(fl * 5 + 0), WpM(fl * 5 + 1), WpM(fl * 5 + 2),
            bcomb + fl * D, out_cui, nullptr, N_CUI, 3, mode);
        gemm_split<<<gCode, 256, 0, stream>>>(
            aggCK, hkP[f], hkP[f] /*unused*/, nullptr,
            WpM(fl * 5 + 3), WpM(fl * 5 + 4), WpM(fl * 5 + 4),
            b + (size_t)(fl * 3 + 2) * D, out_code, nullptr, N_CODE, 2, mode);
    }
}

// Round 11
// 1641.883 us; speedup vs baseline: 1.1462x; 1.1462x over previous
//
#include <hip/hip_runtime.h>

typedef unsigned short ushortT;
typedef __attribute__((ext_vector_type(8))) short short8v;
typedef __attribute__((ext_vector_type(4))) float float4v;

constexpr int D = 128;
constexpr int CAPC = 1024;         // entries per bucket per XCD-copy (mean ~512 worst region)
constexpr int OVF_CAP = 1 << 20;   // overflow safety net

// ---------------------------------------------------------- split helpers
__device__ __forceinline__ void splitf(float v, short& h, short& l) {
    unsigned u = __float_as_uint(v);
    unsigned hb = u & 0xffff0000u;
    float r = v - __uint_as_float(hb);
    h = (short)(u >> 16);
    l = (short)(__float_as_uint(r) >> 16);
}
__device__ __forceinline__ unsigned packsplit(float v) {
    unsigned u = __float_as_uint(v);
    unsigned hb = u & 0xffff0000u;
    float r = v - __uint_as_float(hb);
    return hb | (__float_as_uint(r) >> 16);
}
__device__ __forceinline__ float unpackf(unsigned p) {
    return __uint_as_float(p & 0xffff0000u) + __uint_as_float(p << 16);
}

// ------------------------------------------------ phase A: XCD-local scatter
// Copy selector = blockIdx&7 (matches round-robin block->XCD dispatch), so all
// writers of a bkt line share one per-XCD L2 -> lines fill before writeback.
// No per-node count atomics here; counts derived in bucket_finalize.
__global__ void bucket_scatter(const int* __restrict__ ecc, const int* __restrict__ ekc,
                               const int* __restrict__ eck, int Ecc, int Ekc, int Eck,
                               int ncui, int* __restrict__ curC, unsigned* __restrict__ bktC,
                               int* __restrict__ ovfCnt, int* __restrict__ ovf,
                               int* __restrict__ bktOvf, int* __restrict__ cntExtra) {
    int x = blockIdx.x & 7;
    int ET = Ecc + Ekc + Eck;
    for (int e = blockIdx.x * blockDim.x + threadIdx.x; e < ET;
         e += gridDim.x * blockDim.x) {
        int d, s;
        if (e < Ecc)            { s = ecc[e]; d = ecc[Ecc + e]; }
        else if (e < Ecc + Ekc) { int le = e - Ecc; s = ekc[le]; d = ncui + ekc[Ekc + le]; }
        else                    { int le = e - Ecc - Ekc; s = eck[le]; d = 2 * ncui + eck[Eck + le]; }
        int b = d >> 8;
        int p = atomicAdd(&curC[(b * 8 + x) * 16], 1);
        if (p < CAPC) {
            bktC[((size_t)b * 8 + x) * CAPC + p] = ((unsigned)(d & 255) << 24) | (unsigned)s;
        } else {
            int q = atomicAdd(ovfCnt, 1);
            if (q < OVF_CAP) {
                ovf[q * 2] = s; ovf[q * 2 + 1] = d;
                atomicAdd(&bktOvf[b], 1);
                atomicAdd(&cntExtra[d], 1);
            }
        }
    }
}

// --------------------------- phase B: per-bucket totals -> bucket base offsets
__global__ __launch_bounds__(1024) void bucket_sums(const int* __restrict__ curC,
                                                    const int* __restrict__ bktOvf,
                                                    int NB, int NT, int* __restrict__ bktBase,
                                                    int* __restrict__ offs) {
    __shared__ int s[1024];
    int t = threadIdx.x;
    int tot = 0;
    if (t < NB) {
        #pragma unroll
        for (int x = 0; x < 8; ++x) {
            int c = curC[(t * 8 + x) * 16];
            tot += (c > CAPC) ? CAPC : c;
        }
        tot += bktOvf[t];
    }
    s[t] = tot;
    __syncthreads();
    for (int d = 1; d < 1024; d <<= 1) {
        int u = (t >= d) ? s[t - d] : 0;
        __syncthreads();
        s[t] += u;
        __syncthreads();
    }
    if (t < NB) bktBase[t] = s[t] - tot;           // exclusive base
    if (t == 0) { bktBase[NB] = s[1023]; offs[NT] = s[1023]; }
}

// ------- phase C: per-bucket finalize: count + local scan + offs/inv/cur + place
// One block per bucket (256 nodes). Stage all copies' entries in LDS (<=8192),
// LDS-count 256 nodes, 256-wide scan, write offs/inv/cur, scatter csr into the
// bucket's contiguous window (L2-local, full lines).
__global__ __launch_bounds__(256) void bucket_finalize(
    const unsigned* __restrict__ bktC, const int* __restrict__ curC,
    const int* __restrict__ cntExtra, const int* __restrict__ bktBase, int NT,
    int* __restrict__ offs, int* __restrict__ cur, float* __restrict__ inv,
    int* __restrict__ csr) {
    __shared__ unsigned stage[8 * CAPC];
    __shared__ int lcnt[256], lofs[256], lcnt2[256], xbase[9];
    int b = blockIdx.x;
    int t = threadIdx.x;
    lcnt[t] = 0;
    lcnt2[t] = 0;
    if (t == 0) {
        int acc = 0;
        #pragma unroll
        for (int x = 0; x < 8; ++x) {
            xbase[x] = acc;
            int c = curC[(b * 8 + x) * 16];
            acc += (c > CAPC) ? CAPC : c;
        }
        xbase[8] = acc;
    }
    __syncthreads();
    int ntot = xbase[8];
    // copy copies -> stage, counting nodes
    #pragma unroll
    for (int x = 0; x < 8; ++x) {
        int base = xbase[x], n = xbase[x + 1] - base;
        const unsigned* src = bktC + ((size_t)b * 8 + x) * CAPC;
        for (int i = t; i < n; i += 256) {
            unsigned e = src[i];
            stage[base + i] = e;
            atomicAdd(&lcnt[e >> 24], 1);
        }
    }
    __syncthreads();
    int g = b * 256 + t;
    int extra = (g < NT) ? cntExtra[g] : 0;
    int tot = lcnt[t] + extra;
    lofs[t] = tot;
    __syncthreads();
    for (int d = 1; d < 256; d <<= 1) {
        int u = (t >= d) ? lofs[t - d] : 0;
        __syncthreads();
        lofs[t] += u;
        __syncthreads();
    }
    int excl = lofs[t] - tot;
    int base = bktBase[b];
    if (g < NT) {
        offs[g] = base + excl;
        cur[g]  = base + excl + lcnt[t];   // ovf entries land after local ones
        inv[g]  = 1.f / fmaxf((float)tot, 1.f);
    }
    __syncthreads();
    lofs[t] = excl;                        // exclusive offsets for placement
    __syncthreads();
    for (int i = t; i < ntot; i += 256) {
        unsigned e = stage[i];
        int ld = e >> 24;
        int ord = atomicAdd(&lcnt2[ld], 1);
        csr[base + lofs[ld] + ord] = (int)(e & 0xFFFFFFu);
    }
}

// overflow drain (normally count==0; always launched for graph-capture safety)
__global__ void place_ovf(const int* __restrict__ ovfCnt, const int* __restrict__ ovf,
                          int* __restrict__ cur, int* __restrict__ csr) {
    int n = *ovfCnt;
    if (n > OVF_CAP) n = OVF_CAP;
    for (int i = blockIdx.x * blockDim.x + threadIdx.x; i < n;
         i += gridDim.x * blockDim.x) {
        int s = ovf[i * 2], d = ovf[i * 2 + 1];
        int p = atomicAdd(&cur[d], 1);
        csr[p] = s;
    }
}

// --------------------------------- weight reorder to MFMA-frag-major hi/lo
__global__ void prep_w(const float* __restrict__ Wl, const float* __restrict__ Wr,
                       const float* __restrict__ b, ushortT* __restrict__ Wp,
                       float* __restrict__ bcomb) {
    if (blockIdx.x == 160) {
        for (int t = threadIdx.x; t < 512; t += 256) {
            int fl = t >> 7, c = t & 127;
            bcomb[t] = b[(fl * 3 + 0) * D + c] + b[(fl * 3 + 1) * D + c];
        }
        return;
    }
    int id = blockIdx.x * 256 + threadIdx.x;
    int mat = id >> 11;
    int slot = id & 2047;
    int nt = slot >> 8, rem = slot & 255, ks = rem >> 6, lane = rem & 63;
    int row = nt * 16 + (lane & 15);
    int k0 = ks * 32 + ((lane >> 4) << 3);
    int fl = mat / 5, j = mat % 5;
    const float* s1;
    const float* s2 = nullptr;
    if (j < 2)       s1 = Wl + (size_t)(fl * 3 + j) * D * D;
    else if (j == 2) { s1 = Wr + (size_t)(fl * 3 + 0) * D * D;
                       s2 = Wr + (size_t)(fl * 3 + 1) * D * D; }
    else if (j == 3) s1 = Wl + (size_t)(fl * 3 + 2) * D * D;
    else             s1 = Wr + (size_t)(fl * 3 + 2) * D * D;

    unsigned hw[4], lw[4];
    #pragma unroll
    for (int q = 0; q < 4; ++q) {
        short h0, l0, h1, l1;
        float v0 = s1[row * D + k0 + 2 * q];
        float v1 = s1[row * D + k0 + 2 * q + 1];
        if (s2) { v0 += s2[row * D + k0 + 2 * q]; v1 += s2[row * D + k0 + 2 * q + 1]; }
        splitf(v0, h0, l0);
        splitf(v1, h1, l1);
        hw[q] = (unsigned short)h0 | ((unsigned)(unsigned short)h1 << 16);
        lw[q] = (unsigned short)l0 | ((unsigned)(unsigned short)l1 << 16);
    }
    ushortT* dh = Wp + (size_t)mat * 32768 + slot * 8;
    *(uint4*)dh           = make_uint4(hw[0], hw[1], hw[2], hw[3]);
    *(uint4*)(dh + 16384) = make_uint4(lw[0], lw[1], lw[2], lw[3]);
}

// ----------------------------------------------------- CSR mean aggregation
__global__ void agg_all(const float* __restrict__ src_cui_f, const float* __restrict__ src_code_f,
                        const unsigned* __restrict__ src_cui_p, const unsigned* __restrict__ src_code_p,
                        int packed, const int* __restrict__ csr, const int* __restrict__ offs,
                        const float* __restrict__ inv, int ncui, int ncode,
                        unsigned* __restrict__ outP) {
    int NT = 2 * ncui + ncode;
    int gw = (int)((blockIdx.x * (size_t)blockDim.x + threadIdx.x) >> 6);
    int lane = threadIdx.x & 63;
    if (gw >= NT) return;
    bool isCode = (gw >= ncui) && (gw < 2 * ncui);
    int st = offs[gw], en = offs[gw + 1];
    float ax[8], ay[8];
    #pragma unroll
    for (int j = 0; j < 8; ++j) { ax[j] = 0.f; ay[j] = 0.f; }
    int e = st;
    if (!packed) {
        const float* s = isCode ? src_code_f : src_cui_f;
        for (; e + 8 <= en; e += 8) {
            int idx[8];
            #pragma unroll
            for (int j = 0; j < 8; ++j) idx[j] = csr[e + j];
            #pragma unroll
            for (int j = 0; j < 8; ++j) {
                float2 q = ((const float2*)(s + (size_t)idx[j] * D))[lane];
                ax[j] += q.x; ay[j] += q.y;
            }
        }
        for (; e + 4 <= en; e += 4) {
            int idx[4];
            #pragma unroll
            for (int j = 0; j < 4; ++j) idx[j] = csr[e + j];
            #pragma unroll
            for (int j = 0; j < 4; ++j) {
                float2 q = ((const float2*)(s + (size_t)idx[j] * D))[lane];
                ax[j] += q.x; ay[j] += q.y;
            }
        }
        for (; e < en; ++e) {
            float2 q = ((const float2*)(s + (size_t)csr[e] * D))[lane];
            ax[0] += q.x; ay[0] += q.y;
        }
    } else {
        const unsigned* s = isCode ? src_code_p : src_cui_p;
        for (; e + 8 <= en; e += 8) {
            int idx[8];
            #pragma unroll
            for (int j = 0; j < 8; ++j) idx[j] = csr[e + j];
            #pragma unroll
            for (int j = 0; j < 8; ++j) {
                uint2 q = ((const uint2*)(s + (size_t)idx[j] * D))[lane];
                ax[j] += unpackf(q.x); ay[j] += unpackf(q.y);
            }
        }
        for (; e + 4 <= en; e += 4) {
            int idx[4];
            #pragma unroll
            for (int j = 0; j < 4; ++j) idx[j] = csr[e + j];
            #pragma unroll
            for (int j = 0; j < 4; ++j) {
                uint2 q = ((const uint2*)(s + (size_t)idx[j] * D))[lane];
                ax[j] += unpackf(q.x); ay[j] += unpackf(q.y);
            }
        }
        for (; e < en; ++e) {
            uint2 q = ((const uint2*)(s + (size_t)csr[e] * D))[lane];
            ax[0] += unpackf(q.x); ay[0] += unpackf(q.y);
        }
    }
    float sc = inv[gw];
    float r0 = (((ax[0] + ax[1]) + (ax[2] + ax[3])) + ((ax[4] + ax[5]) + (ax[6] + ax[7]))) * sc;
    float r1 = (((ay[0] + ay[1]) + (ay[2] + ay[3])) + ((ay[4] + ay[5]) + (ay[6] + ay[7]))) * sc;
    ((uint2*)(outP + (size_t)gw * D))[lane] = make_uint2(packsplit(r0), packsplit(r1));
}

// -------------------------------------------------- split-bf16 MFMA GEMM
__global__ __launch_bounds__(256, 2) void gemm_split(
    const unsigned* __restrict__ A0, const unsigned* __restrict__ A1,
    const unsigned* __restrict__ A2, const float* __restrict__ Alast_f32,
    const ushortT* __restrict__ W0, const ushortT* __restrict__ W1,
    const ushortT* __restrict__ W2, const float* __restrict__ bias,
    float* __restrict__ outF, unsigned* __restrict__ outP,
    int M, int nPairs, int mode) {
    __shared__ ushortT wlds[32768];

    int tid = threadIdx.x;
    int lane = tid & 63;
    int w = tid >> 6;
    int rowTile = blockIdx.x * 256 + w * 64;
    int rl = lane & 15;
    int kg = (lane >> 4) << 3;

    float4v acc[4][8];
    #pragma unroll
    for (int mt = 0; mt < 4; ++mt)
        #pragma unroll
        for (int nt = 0; nt < 8; ++nt)
            acc[mt][nt] = (float4v){0.f, 0.f, 0.f, 0.f};

    const unsigned* Aarr[3] = {A0, A1, A2};
    const ushortT* Warr[3] = {W0, W1, W2};

    for (int p = 0; p < nPairs; ++p) {
        __syncthreads();
        {
            const ushortT* Wsrc = Warr[p];
            #pragma unroll
            for (int i = 0; i < 16; ++i)
                *(int4*)&wlds[i * 2048 + tid * 8] = *(const int4*)&Wsrc[i * 2048 + tid * 8];
        }
        __syncthreads();
        bool f32A = (Alast_f32 != nullptr) && (p == nPairs - 1);
        const unsigned* A = Aarr[p];
        #pragma unroll
        for (int ks = 0; ks < 4; ++ks) {
            short8v ah[4], al[4];
            #pragma unroll
            for (int mt = 0; mt < 4; ++mt) {
                int row = rowTile + mt * 16 + rl;
                if (row < M) {
                    size_t boff = (size_t)row * D + ks * 32 + kg;
                    if (!f32A) {
                        uint4 q0 = *(const uint4*)(A + boff);
                        uint4 q1 = *(const uint4*)(A + boff + 4);
                        unsigned qa[8] = {q0.x, q0.y, q0.z, q0.w, q1.x, q1.y, q1.z, q1.w};
                        #pragma unroll
                        for (int jj = 0; jj < 8; ++jj) {
                            ah[mt][jj] = (short)(qa[jj] >> 16);
                            al[mt][jj] = (short)(qa[jj] & 0xffffu);
                        }
                    } else {
                        float4 f0 = *(const float4*)(Alast_f32 + boff);
                        float4 f1 = *(const float4*)(Alast_f32 + boff + 4);
                        float fa[8] = {f0.x, f0.y, f0.z, f0.w, f1.x, f1.y, f1.z, f1.w};
                        #pragma unroll
                        for (int jj = 0; jj < 8; ++jj) {
                            short hh, ll;
                            splitf(fa[jj], hh, ll);
                            ah[mt][jj] = hh;
                            al[mt][jj] = ll;
                        }
                    }
                } else {
                    #pragma unroll
                    for (int jj = 0; jj < 8; ++jj) { ah[mt][jj] = 0; al[mt][jj] = 0; }
                }
            }
            #pragma unroll
            for (int nt = 0; nt < 8; ++nt) {
                short8v bh = *(const short8v*)&wlds[nt * 2048 + ks * 512 + lane * 8];
                short8v bl = *(const short8v*)&wlds[16384 + nt * 2048 + ks * 512 + lane * 8];
                #pragma unroll
                for (int mt = 0; mt < 4; ++mt)
                    acc[mt][nt] = __builtin_amdgcn_mfma_f32_16x16x32_bf16(ah[mt], bh, acc[mt][nt], 0, 0, 0);
                #pragma unroll
                for (int mt = 0; mt < 4; ++mt)
                    acc[mt][nt] = __builtin_amdgcn_mfma_f32_16x16x32_bf16(ah[mt], bl, acc[mt][nt], 0, 0, 0);
                #pragma unroll
                for (int mt = 0; mt < 4; ++mt)
                    acc[mt][nt] = __builtin_amdgcn_mfma_f32_16x16x32_bf16(al[mt], bh, acc[mt][nt], 0, 0, 0);
            }
        }
    }

    #pragma unroll
    for (int nt = 0; nt < 8; ++nt) {
        int col = nt * 16 + rl;
        float bv = bias[col];
        #pragma unroll
        for (int mt = 0; mt < 4; ++mt) {
            int r0 = rowTile + mt * 16 + ((lane >> 4) << 2);
            float4v c = acc[mt][nt];
            #pragma unroll
            for (int r = 0; r < 4; ++r) {
                int row = r0 + r;
                if (row >= M) continue;
                float v = c[r] + bv;
                if (mode == 0) {
                    v = fmaxf(v, 0.f);
                    outP[(size_t)row * D + col] = packsplit(v);
                } else if (mode == 1) {
                    outF[(size_t)row * D + col] = v;
                } else {
                    float* pp = outF + (size_t)row * D + col;
                    *pp = fmaxf(*pp, v);
                }
            }
        }
    }
}

// ------------------------------------------------------------------- driver
extern "C" void kernel_launch(void* const* d_in, const int* in_sizes, int n_in,
                              void* d_out, int out_size, void* d_ws, size_t ws_size,
                              hipStream_t stream) {
    const float* x_cui  = (const float*)d_in[0];
    const float* x_code = (const float*)d_in[1];
    const int*   ei_cc  = (const int*)d_in[2];
    const int*   ei_kc  = (const int*)d_in[3];
    const int*   ei_ck  = (const int*)d_in[4];
    const float* Wl     = (const float*)d_in[5];
    const float* Wr     = (const float*)d_in[6];
    const float* b      = (const float*)d_in[7];

    const int N_CUI  = in_sizes[0] / D;
    const int N_CODE = in_sizes[1] / D;
    const int E_CC   = in_sizes[2] / 2;
    const int E_KC   = in_sizes[3] / 2;
    const int E_CK   = in_sizes[4] / 2;
    const int NT = 2 * N_CUI + N_CODE;
    const int ET = E_CC + E_KC + E_CK;
    const int NB = (NT + 255) >> 8;          // buckets (977 here; must be <=1024)

    char* ws = (char*)d_ws;
    size_t off = 0;
    auto alloc = [&](size_t bytes) -> char* {
        char* p = ws + off;
        off += (bytes + 255) & ~(size_t)255;
        return p;
    };

    // zero-init region (one memset): copy cursors + ovf cursor + ovf counts + extra counts
    int*      curC     = (int*)alloc((size_t)NB * 8 * 16 * 4);
    int*      ovfCnt   = (int*)alloc(64);
    int*      bktOvf   = (int*)alloc((size_t)NB * 4);
    int*      cntExtra = (int*)alloc((size_t)NT * 4);
    size_t cntBytes = off;

    int*      offsAll  = (int*)alloc(((size_t)NT + 4) * 4);
    int*      curAll   = (int*)alloc((size_t)NT * 4);
    float*    invAll   = (float*)alloc((size_t)NT * 4);
    int*      bktBase  = (int*)alloc(((size_t)NB + 1) * 4);
    int*      csrAll   = (int*)alloc((size_t)ET * 4);
    ushortT*  Wp       = (ushortT*)alloc((size_t)20 * 32768 * 2);
    float*    bcomb    = (float*)alloc(512 * 4);
    unsigned* aggP     = (unsigned*)alloc((size_t)NT * D * 4);
    unsigned* hcuiP0   = (unsigned*)alloc((size_t)N_CUI * D * 4);
    unsigned* hcuiP1   = (unsigned*)alloc((size_t)N_CUI * D * 4);
    unsigned* hcodeP0  = (unsigned*)alloc((size_t)N_CODE * D * 4);
    unsigned* hcodeP1  = (unsigned*)alloc((size_t)N_CODE * D * 4);

    // bktC/ovf ALIASED into aggP (used only during CSR build, which completes
    // stream-ordered before the first agg_all writes aggP). 32MB + 8MB < 128MB.
    unsigned* bktC = aggP;
    int*      ovf  = (int*)(aggP + (size_t)NB * 8 * CAPC);

    float* out_cui  = (float*)d_out;
    float* out_code = (float*)d_out + (size_t)N_CUI * D;

    unsigned* hcP[2] = {hcuiP0, hcuiP1};
    unsigned* hkP[2] = {hcodeP0, hcodeP1};

    const unsigned* aggCC = aggP;
    const unsigned* aggKC = aggP + (size_t)N_CUI * D;
    const unsigned* aggCK = aggP + (size_t)2 * N_CUI * D;

    // ---- CSR build: XCD-local scatter -> bucket bases -> per-bucket finalize ----
    hipMemsetAsync(d_ws, 0, cntBytes, stream);
    bucket_scatter<<<2048, 256, 0, stream>>>(ei_cc, ei_kc, ei_ck, E_CC, E_KC, E_CK,
                                             N_CUI, curC, bktC, ovfCnt, ovf, bktOvf, cntExtra);
    bucket_sums<<<1, 1024, 0, stream>>>(curC, bktOvf, NB, NT, bktBase, offsAll);
    bucket_finalize<<<NB, 256, 0, stream>>>(bktC, curC, cntExtra, bktBase, NT,
                                            offsAll, curAll, invAll, csrAll);
    place_ovf<<<64, 256, 0, stream>>>(ovfCnt, ovf, curAll, csrAll);
    prep_w<<<161, 256, 0, stream>>>(Wl, Wr, b, Wp, bcomb);

    int aggGrid = (NT + 3) / 4;
    int gCui = (N_CUI + 255) / 256;
    int gCode = (N_CODE + 255) / 256;
    auto WpM = [&](int m) { return (const ushortT*)(Wp + (size_t)m * 32768); };

    // ---- layer 0: shared aggregation, then per-filter transforms ----
    agg_all<<<aggGrid, 256, 0, stream>>>(x_cui, x_code, nullptr, nullptr, 0,
                                         csrAll, offsAll, invAll, N_CUI, N_CODE, aggP);
    for (int f = 0; f < 2; ++f) {
        int fl = f * 2;
        gemm_split<<<gCui, 256, 0, stream>>>(
            aggCC, aggKC, aggCC /*unused*/, x_cui,
            WpM(fl * 5 + 0), WpM(fl * 5 + 1), WpM(fl * 5 + 2),
            bcomb + fl * D, nullptr, hcP[f], N_CUI, 3, 0);
    }
    for (int f = 0; f < 2; ++f) {
        int fl = f * 2;
        gemm_split<<<gCode, 256, 0, stream>>>(
            aggCK, aggCK /*unused*/, aggCK /*unused*/, x_code,
            WpM(fl * 5 + 3), WpM(fl * 5 + 4), WpM(fl * 5 + 4),
            b + (size_t)(fl * 3 + 2) * D, nullptr, hkP[f], N_CODE, 2, 0);
    }

    // ---- layer 1: per-filter aggregation + final transforms ----
    for (int f = 0; f < 2; ++f) {
        int fl = f * 2 + 1;
        int mode = (f == 0) ? 1 : 2;
        agg_all<<<aggGrid, 256, 0, stream>>>(nullptr, nullptr, hcP[f], hkP[f], 1,
                                             csrAll, offsAll, invAll, N_CUI, N_CODE, aggP);
        gemm_split<<<gCui, 256, 0, stream>>>(
            aggCC, aggKC, hcP[f], nullptr,
            WpM(fl * 5 + 0), WpM(fl * 5 + 1), WpM(fl * 5 + 2),
            bcomb + fl * D, out_cui, nullptr, N_CUI, 3, mode);
        gemm_split<<<gCode, 256, 0, stream>>>(
            aggCK, hkP[f], hkP[f] /*unused*/, nullptr,
            WpM(fl * 5 + 3), WpM(fl * 5 + 4), WpM(fl * 5 + 4),
            b + (size_t)(fl * 3 + 2) * D, out_code, nullptr, N_CODE, 2, mode);
    }
}